// Round 7
// baseline (97.705 us; speedup 1.0000x reference)
//
#include <hip/hip_runtime.h>
#include <hip/hip_bf16.h>
#include <hip/hip_fp16.h>

#define BDIM    128   // batch size, fixed by problem
#define NGROUPS 4     // batch groups (32 batches each), one per XCD pair
#define GCOLS   32    // batch columns per group
#define ROWB    (GCOLS * 2)            // bytes per xTh row = 64
#define EBLK    2048  // edge-kernel blocks (divisible by 8)
#define RANKS   (EBLK / NGROUPS)       // blocks per group = 512
#define WPG     (RANKS * 4)            // waves per group = 2048
#define S1BLK   (NGROUPS * 8)          // stage-1 edge-reduce blocks = 32
#define HBLK2   8     // stage-1 h-reduce blocks
#define RPS     (RANKS / 8)            // ranks per stage-1 block = 64

// ---------------------------------------------------------------------------
// Kernel 1: transpose+convert x (B=128,N) f32 -> xTh[g][N][32] fp16 slices,
// FUSED with h-term partials: hp[block][b] = sum_{n in tile} x[b,n]*h[n].
// Slice g holds batches [32g,32g+32) -> 3.2MB, L2-resident per XCD pair.
// ---------------------------------------------------------------------------
__global__ __launch_bounds__(256) void transpose_h_kernel(
    const float* __restrict__ x, const float* __restrict__ h,
    __half* __restrict__ xTh, float* __restrict__ hp, int N) {
  __shared__ float tile[64][BDIM + 1];
  __shared__ float sh[64];
  __shared__ float red2[2][BDIM];
  const int tid = threadIdx.x;
  const int n0  = blockIdx.x * 64;

  const int tn  = tid & 63;
  const int tb0 = tid >> 6;
  const int n   = n0 + tn;
  if (n < N) {
    for (int b = tb0; b < BDIM; b += 4) tile[tn][b] = x[(size_t)b * N + n];
  } else {
    for (int b = tb0; b < BDIM; b += 4) tile[tn][b] = 0.f;
  }
  if (tid < 64) sh[tid] = (n0 + tid < N) ? h[n0 + tid] : 0.f;
  __syncthreads();

  // h-term partial: thread (half, b) sums 32 n's
  const int hb   = tid & 127;
  const int half = tid >> 7;
  float hacc = 0.f;
#pragma unroll
  for (int m = 0; m < 32; ++m) {
    const int nl = half * 32 + m;
    hacc += tile[nl][hb] * sh[nl];
  }
  red2[half][hb] = hacc;

  // transpose store: thread = (k, g2, c2); 16 lanes write 64B contiguous
  const int c2 = tid & 15;
  const int g2 = (tid >> 4) & 3;
  const int k  = tid >> 6;
  for (int it = 0; it < 16; ++it) {
    const int nl = it * 4 + k;
    if (n0 + nl < N) {
      const float a = tile[nl][g2 * GCOLS + 2 * c2];
      const float b = tile[nl][g2 * GCOLS + 2 * c2 + 1];
      __half2* dst = (__half2*)(xTh + ((size_t)g2 * N + (n0 + nl)) * GCOLS + 2 * c2);
      *dst = __floats2half2_rn(a, b);
    }
  }
  __syncthreads();
  if (tid < BDIM) hp[(size_t)blockIdx.x * BDIM + tid] = red2[0][tid] + red2[1][tid];
}

// ---------------------------------------------------------------------------
// 8-column packed-fp16 product, mixed-precision f32 accumulate.
// ---------------------------------------------------------------------------
__device__ __forceinline__ void fma8(float* acc, int4 vi, int4 vj, float Jv) {
  const int wi[4] = {vi.x, vi.y, vi.z, vi.w};
  const int wj[4] = {vj.x, vj.y, vj.z, vj.w};
#pragma unroll
  for (int w = 0; w < 4; ++w) {
    const __half2 hi = __builtin_bit_cast(__half2, wi[w]);
    const __half2 hj = __builtin_bit_cast(__half2, wj[w]);
    const __half2 p  = __hmul2(hi, hj);
    acc[2 * w]     += __low2float(p)  * Jv;
    acc[2 * w + 1] += __high2float(p) * Jv;
  }
}

// ---------------------------------------------------------------------------
// Kernel 2: edge interactions — two-deep software pipeline, named register
// buffers. Per 32-edge step: 6 index loads (sequential lines) + 4 int4 row
// gathers (16 random 64B lines each pair). Body issues gathers(s+1) and
// indices(s+2) BEFORE consuming payload(s) -> ~8 gathers + 6 idx loads in
// flight per wave. sched_barrier(0) pins the issue/consume split so the
// compiler's counted vmcnt survives. Steps are grid-strided across the
// group's waves for perfect balance. Tail masked via clamped index + J=0.
// Block -> (group, rank): group g=(blockIdx&7)>>1 -> XCD pair {2g,2g+1},
// 3.2MB slice stays L2-resident.
// ---------------------------------------------------------------------------
__global__ __launch_bounds__(256, 6) void edge_kernel(
    const __half* __restrict__ xTh, const float* __restrict__ J,
    const int* __restrict__ ei, const int* __restrict__ ej,
    float* __restrict__ partials, int E, int N) {
  const int tid  = threadIdx.x;
  const int g    = (blockIdx.x & 7) >> 1;
  const int rank = (blockIdx.x >> 3) * 2 + (blockIdx.x & 1);
  const int wave = tid >> 6;
  const int lane = tid & 63;
  const int k    = lane >> 2;          // edge sub-index 0..15
  const char* xgl = (const char*)xTh + (size_t)g * N * ROWB + (lane & 3) * 16;

  const int gw = rank * 4 + wave;      // wave id within group [0, WPG)
  const int Tg = (E + 31) >> 5;        // total 32-edge steps
  const int ns = (gw < Tg) ? (Tg - gw + WPG - 1) / WPG : 0;

#define LOAD_IDX(sstep, iA, jA, JA, iB, jB, JB)                     \
  do {                                                              \
    const int e0_ = (gw + (sstep) * WPG) * 32;                      \
    const int eA_ = e0_ + k, eB_ = eA_ + 16;                        \
    const int eAc_ = min(eA_, E - 1), eBc_ = min(eB_, E - 1);       \
    iA = ei[eAc_]; jA = ej[eAc_];                                   \
    JA = (eA_ < E) ? J[eAc_] : 0.f;                                 \
    iB = ei[eBc_]; jB = ej[eBc_];                                   \
    JB = (eB_ < E) ? J[eBc_] : 0.f;                                 \
  } while (0)

#define GATHER(vA, wA, vB, wB, iA, jA, iB, jB)                      \
  do {                                                              \
    vA = *(const int4*)(xgl + (unsigned)(iA) * ROWB);               \
    wA = *(const int4*)(xgl + (unsigned)(jA) * ROWB);               \
    vB = *(const int4*)(xgl + (unsigned)(iB) * ROWB);               \
    wB = *(const int4*)(xgl + (unsigned)(jB) * ROWB);               \
  } while (0)

  float acc[8] = {0.f, 0.f, 0.f, 0.f, 0.f, 0.f, 0.f, 0.f};

  int   iA0, jA0, iB0, jB0, iA1, jA1, iB1, jB1;
  float JA0, JB0, JA1, JB1;
  float JhA0, JhB0, JhA1, JhB1;
  int4  viA0, vjA0, viB0, vjB0, viA1, vjA1, viB1, vjB1;

  int s = 0;
  if (ns > 0) {
    // prologue: payload(0) and idx(1) in flight
    LOAD_IDX(0, iA0, jA0, JA0, iB0, jB0, JB0);
    GATHER(viA0, vjA0, viB0, vjB0, iA0, jA0, iB0, jB0);
    JhA0 = JA0; JhB0 = JB0;
    {
      const int s1 = (ns > 1) ? 1 : 0;
      LOAD_IDX(s1, iA1, jA1, JA1, iB1, jB1, JB1);
    }

    for (; s + 2 <= ns; s += 2) {
      // half A: issue payload(s+1) + idx(s+2); consume payload(s)
      GATHER(viA1, vjA1, viB1, vjB1, iA1, jA1, iB1, jB1);
      JhA1 = JA1; JhB1 = JB1;
      {
        const int s2 = min(s + 2, ns - 1);
        LOAD_IDX(s2, iA0, jA0, JA0, iB0, jB0, JB0);
      }
      __builtin_amdgcn_sched_barrier(0);
      fma8(acc, viA0, vjA0, JhA0);
      fma8(acc, viB0, vjB0, JhB0);

      // half B: issue payload(s+2) + idx(s+3); consume payload(s+1)
      GATHER(viA0, vjA0, viB0, vjB0, iA0, jA0, iB0, jB0);
      JhA0 = JA0; JhB0 = JB0;
      {
        const int s3 = min(s + 3, ns - 1);
        LOAD_IDX(s3, iA1, jA1, JA1, iB1, jB1, JB1);
      }
      __builtin_amdgcn_sched_barrier(0);
      fma8(acc, viA1, vjA1, JhA1);
      fma8(acc, viB1, vjB1, JhB1);
    }
    if (s < ns) {  // odd leftover step: payload sits in buffer 0
      fma8(acc, viA0, vjA0, JhA0);
      fma8(acc, viB0, vjB0, JhB0);
    }
  }
#undef LOAD_IDX
#undef GATHER

  // combine the 16 k-lanes sharing each column quarter (xor 4,8,16,32)
#pragma unroll
  for (int off = 4; off < 64; off <<= 1)
#pragma unroll
    for (int w = 0; w < 8; ++w) acc[w] += __shfl_xor(acc[w], off);

  __shared__ float red[4][GCOLS];
  if (lane < 4)
#pragma unroll
    for (int w = 0; w < 8; ++w) red[wave][(lane & 3) * 8 + w] = acc[w];
  __syncthreads();
  if (tid < GCOLS) {
    const float sum = red[0][tid] + red[1][tid] + red[2][tid] + red[3][tid];
    partials[((size_t)g * RANKS + rank) * GCOLS + tid] = sum;
  }
}

// ---------------------------------------------------------------------------
// Kernel 3: stage-1 reduce. Blocks [0,32): edge partials (g,s) sum 64 rank
// rows -> P2. Blocks [32,40): h partials, block s sums rows r%8==s -> hp2.
// ---------------------------------------------------------------------------
__global__ __launch_bounds__(256) void reduce1_kernel(
    const float* __restrict__ P, const float* __restrict__ hp,
    float* __restrict__ P2, float* __restrict__ hp2, int hrows) {
  __shared__ float red[8][GCOLS];
  __shared__ float redh[2][BDIM];
  if (blockIdx.x < S1BLK) {
    const int g  = blockIdx.x >> 3;
    const int s  = blockIdx.x & 7;
    const int rl = threadIdx.x >> 5;
    const int c  = threadIdx.x & 31;
    float acc = 0.f;
    for (int rr = rl; rr < RPS; rr += 8)
      acc += P[((size_t)g * RANKS + s * RPS + rr) * GCOLS + c];
    red[rl][c] = acc;
    __syncthreads();
    if (threadIdx.x < GCOLS) {
      float sum = 0.f;
      for (int r = 0; r < 8; ++r) sum += red[r][threadIdx.x];
      P2[(size_t)blockIdx.x * GCOLS + threadIdx.x] = sum;
    }
  } else {
    const int s  = blockIdx.x - S1BLK;
    const int b  = threadIdx.x & 127;
    const int rg = threadIdx.x >> 7;
    float acc = 0.f;
    for (int r = s + 8 * rg; r < hrows; r += 16)
      acc += hp[(size_t)r * BDIM + b];
    redh[rg][b] = acc;
    __syncthreads();
    if (threadIdx.x < BDIM)
      hp2[(size_t)s * BDIM + threadIdx.x] = redh[0][threadIdx.x] + redh[1][threadIdx.x];
  }
}

// ---------------------------------------------------------------------------
// Kernel 4: final: out[b] = sum_s hp2[s][b] + sum_s P2[(g*8+s)][c].
// ---------------------------------------------------------------------------
__global__ __launch_bounds__(128) void reduce2_kernel(
    const float* __restrict__ P2, const float* __restrict__ hp2,
    float* __restrict__ out) {
  const int b = threadIdx.x;
  const int g = b >> 5;
  const int c = b & 31;
  float acc = 0.f;
  for (int s = 0; s < 8; ++s) acc += hp2[(size_t)s * BDIM + b];
  for (int s = 0; s < 8; ++s) acc += P2[(size_t)(g * 8 + s) * GCOLS + c];
  out[b] = acc;
}

extern "C" void kernel_launch(void* const* d_in, const int* in_sizes, int n_in,
                              void* d_out, int out_size, void* d_ws, size_t ws_size,
                              hipStream_t stream) {
  const float* x  = (const float*)d_in[0];
  const float* h  = (const float*)d_in[1];
  const float* J  = (const float*)d_in[2];
  const int*   ei = (const int*)d_in[3];
  const int*   ej = (const int*)d_in[4];
  float* out = (float*)d_out;

  const int N = in_sizes[1];   // 50000
  const int E = in_sizes[2];   // 1600000

  const int tblocks = (N + 63) / 64;

  // ws layout: xTh (4*N*32 halves) | P (EBLK*32) | P2 (32*32) | hp (tblocks*128) | hp2 (8*128)
  __half* xTh = (__half*)d_ws;
  float* P   = (float*)(xTh + (size_t)NGROUPS * N * GCOLS);
  float* P2  = P   + (size_t)EBLK * GCOLS;
  float* hp  = P2  + (size_t)S1BLK * GCOLS;
  float* hp2 = hp  + (size_t)tblocks * BDIM;

  // 1) transpose + fp16 convert + h-term partials
  transpose_h_kernel<<<tblocks, 256, 0, stream>>>(x, h, xTh, hp, N);

  // 2) edge interactions (4 batch groups, XCD-affine, 2-deep pipeline)
  edge_kernel<<<EBLK, 256, 0, stream>>>(xTh, J, ei, ej, P, E, N);

  // 3) stage-1 reduce (edge partials + h partials)
  reduce1_kernel<<<S1BLK + HBLK2, 256, 0, stream>>>(P, hp, P2, hp2, tblocks);

  // 4) final deterministic reduce (overwrites d_out)
  reduce2_kernel<<<1, BDIM, 0, stream>>>(P2, hp2, out);
}

// Round 8
// 83.638 us; speedup vs baseline: 1.1682x; 1.1682x over previous
//
#include <hip/hip_runtime.h>
#include <hip/hip_bf16.h>
#include <hip/hip_fp16.h>

#define BDIM    128   // batch size, fixed by problem
#define NGROUPS 2     // batch groups (64 batches each), one per XCD quad
#define GCOLS   64    // batch columns per group
#define ROWB    (GCOLS * 2)            // bytes per xTh row = 128 (one L2 line)
#define EBLK    2048  // edge-kernel blocks (divisible by 8)
#define RANKS   (EBLK / NGROUPS)       // blocks per group = 1024
#define CHUNK   256   // edges staged in LDS per block iteration
#define S1BLK   (NGROUPS * 8)          // stage-1 edge-reduce blocks = 16
#define HBLK2   8     // stage-1 h-reduce blocks
#define RPS     (RANKS / 8)            // ranks per stage-1 block = 128

// ---------------------------------------------------------------------------
// Kernel 1: transpose+convert x (B=128,N) f32 -> xTh[g][N][64] fp16 slices,
// FUSED with h-term partials: hp[block][b] = sum_{n in tile} x[b,n]*h[n].
// Slice g holds batches [64g,64g+64): 6.4MB, mostly L2-resident per XCD quad.
// Rows are 128B-aligned single L2 lines.
// ---------------------------------------------------------------------------
__global__ __launch_bounds__(256) void transpose_h_kernel(
    const float* __restrict__ x, const float* __restrict__ h,
    __half* __restrict__ xTh, float* __restrict__ hp, int N) {
  __shared__ float tile[64][BDIM + 1];
  __shared__ float sh[64];
  __shared__ float red2[2][BDIM];
  const int tid = threadIdx.x;
  const int n0  = blockIdx.x * 64;

  const int tn  = tid & 63;
  const int tb0 = tid >> 6;
  const int n   = n0 + tn;
  if (n < N) {
    for (int b = tb0; b < BDIM; b += 4) tile[tn][b] = x[(size_t)b * N + n];
  } else {
    for (int b = tb0; b < BDIM; b += 4) tile[tn][b] = 0.f;
  }
  if (tid < 64) sh[tid] = (n0 + tid < N) ? h[n0 + tid] : 0.f;
  __syncthreads();

  // h-term partial: thread (half, b) sums 32 n's
  const int hb   = tid & 127;
  const int half = tid >> 7;
  float hacc = 0.f;
#pragma unroll
  for (int m = 0; m < 32; ++m) {
    const int nl = half * 32 + m;
    hacc += tile[nl][hb] * sh[nl];
  }
  red2[half][hb] = hacc;

  // transpose store: thread = (k, g2, c2); 32 lanes write 128B contiguous
  const int c2 = tid & 31;         // column pair within group 0..31
  const int g2 = (tid >> 5) & 1;   // group
  const int k  = tid >> 6;         // n sub-row 0..3
  for (int it = 0; it < 16; ++it) {
    const int nl = it * 4 + k;
    if (n0 + nl < N) {
      const float a = tile[nl][g2 * GCOLS + 2 * c2];
      const float b = tile[nl][g2 * GCOLS + 2 * c2 + 1];
      __half2* dst = (__half2*)(xTh + ((size_t)g2 * N + (n0 + nl)) * GCOLS + 2 * c2);
      *dst = __floats2half2_rn(a, b);
    }
  }
  __syncthreads();
  if (tid < BDIM) hp[(size_t)blockIdx.x * BDIM + tid] = red2[0][tid] + red2[1][tid];
}

// ---------------------------------------------------------------------------
// 8-column fp16 product with v_fma_mix_f32 accumulate (fp16 src folded into
// the f32 FMA -> 3 VALU per 2 columns instead of 5).
// ---------------------------------------------------------------------------
__device__ __forceinline__ void fma8mix(float* acc, int4 vi, int4 vj, float Jv) {
  const int wi[4] = {vi.x, vi.y, vi.z, vi.w};
  const int wj[4] = {vj.x, vj.y, vj.z, vj.w};
#pragma unroll
  for (int w = 0; w < 4; ++w) {
    const __half2 hi = __builtin_bit_cast(__half2, wi[w]);
    const __half2 hj = __builtin_bit_cast(__half2, wj[w]);
    const int p = __builtin_bit_cast(int, __hmul2(hi, hj));
    asm("v_fma_mix_f32 %0, %1, %2, %0 op_sel_hi:[1,0,0]"
        : "+v"(acc[2 * w]) : "v"(p), "v"(Jv));
    asm("v_fma_mix_f32 %0, %1, %2, %0 op_sel:[1,0,0] op_sel_hi:[1,0,0]"
        : "+v"(acc[2 * w + 1]) : "v"(p), "v"(Jv));
  }
}

// ---------------------------------------------------------------------------
// Kernel 2: edge interactions. 8 lanes per edge, each lane gathers 16B of a
// 128B row -> every row access is ONE aligned 128B L2 line (halves the
// per-CU request count vs 64B rows at equal bytes). (i,j,J) packed as int4
// in LDS -> one ds_read_b128 per 8 edges. Chunk of 256 edges staged with
// coalesced loads + register prefetch of the next chunk.
// Block -> (group, rank): group g=(blockIdx&7)>>2 -> XCD quad, slice 6.4MB.
// Tail padded with J=0 -> hot loop branch-free.
// ---------------------------------------------------------------------------
__global__ __launch_bounds__(256) void edge_kernel(
    const __half* __restrict__ xTh, const float* __restrict__ J,
    const int* __restrict__ ei, const int* __restrict__ ej,
    float* __restrict__ P, int E, int N, int epr) {
  const int tid  = threadIdx.x;
  const int g    = (blockIdx.x & 7) >> 2;
  const int rank = (blockIdx.x >> 3) * 4 + (blockIdx.x & 3);
  const int wave = tid >> 6;
  const int lane = tid & 63;
  const int k    = lane >> 3;          // edge sub-index 0..7
  const char* xgl = (const char*)xTh + (size_t)g * N * ROWB + (lane & 7) * 16;

  const int start = rank * epr;
  const int end   = min(start + epr, E);

  __shared__ int4 se[CHUNK];

  // register prefetch of first chunk (issue early, write late)
  int ri = 0, rj = 0;
  float rJ = 0.f;
  {
    const int e = start + tid;
    if (e < end) { ri = ei[e]; rj = ej[e]; rJ = J[e]; }
  }

  float acc[8] = {0.f, 0.f, 0.f, 0.f, 0.f, 0.f, 0.f, 0.f};

  for (int base = start; base < end; base += CHUNK) {
    se[tid] = make_int4(ri, rj, __float_as_int(rJ), 0);
    __syncthreads();

    // issue next chunk's loads; latency hides under the gather loop
    {
      const int e = base + CHUNK + tid;
      ri = 0; rj = 0; rJ = 0.f;
      if (e < end) { ri = ei[e]; rj = ej[e]; rJ = J[e]; }
    }

    const int lbase = wave * 64 + k;
#pragma unroll
    for (int u = 0; u < 8; ++u) {
      const int4  eJ = se[lbase + u * 8];
      const float Jv = __int_as_float(eJ.z);
      const int4 vi = *(const int4*)(xgl + (unsigned)eJ.x * ROWB);
      const int4 vj = *(const int4*)(xgl + (unsigned)eJ.y * ROWB);
      fma8mix(acc, vi, vj, Jv);
    }
    __syncthreads();
  }

  // combine the 8 k-lanes sharing each column eighth (xor 8,16,32)
#pragma unroll
  for (int off = 8; off < 64; off <<= 1)
#pragma unroll
    for (int w = 0; w < 8; ++w) acc[w] += __shfl_xor(acc[w], off);

  __shared__ float red[4][GCOLS];
  if (lane < 8)
#pragma unroll
    for (int w = 0; w < 8; ++w) red[wave][lane * 8 + w] = acc[w];
  __syncthreads();
  if (tid < GCOLS) {
    const float s = red[0][tid] + red[1][tid] + red[2][tid] + red[3][tid];
    P[((size_t)g * RANKS + rank) * GCOLS + tid] = s;
  }
}

// ---------------------------------------------------------------------------
// Kernel 3: stage-1 reduce. Blocks [0,16): edge partials (g,s) sum 128 rank
// rows -> P2. Blocks [16,24): h partials, block s sums rows r%8==s -> hp2.
// ---------------------------------------------------------------------------
__global__ __launch_bounds__(256) void reduce1_kernel(
    const float* __restrict__ P, const float* __restrict__ hp,
    float* __restrict__ P2, float* __restrict__ hp2, int hrows) {
  __shared__ float red[4][GCOLS];
  __shared__ float redh[2][BDIM];
  if (blockIdx.x < S1BLK) {
    const int g  = blockIdx.x >> 3;
    const int s  = blockIdx.x & 7;
    const int rl = threadIdx.x >> 6;  // 0..3
    const int c  = threadIdx.x & 63;
    float acc = 0.f;
    for (int rr = rl; rr < RPS; rr += 4)
      acc += P[((size_t)g * RANKS + s * RPS + rr) * GCOLS + c];
    red[rl][c] = acc;
    __syncthreads();
    if (threadIdx.x < GCOLS) {
      float sum = 0.f;
      for (int r = 0; r < 4; ++r) sum += red[r][threadIdx.x];
      P2[(size_t)blockIdx.x * GCOLS + threadIdx.x] = sum;
    }
  } else {
    const int s  = blockIdx.x - S1BLK;   // 0..7
    const int b  = threadIdx.x & 127;
    const int rg = threadIdx.x >> 7;
    float acc = 0.f;
    for (int r = s + 8 * rg; r < hrows; r += 16)
      acc += hp[(size_t)r * BDIM + b];
    redh[rg][b] = acc;
    __syncthreads();
    if (threadIdx.x < BDIM)
      hp2[(size_t)s * BDIM + threadIdx.x] = redh[0][threadIdx.x] + redh[1][threadIdx.x];
  }
}

// ---------------------------------------------------------------------------
// Kernel 4: final: out[b] = sum_s hp2[s][b] + sum_s P2[(g*8+s)][c].
// ---------------------------------------------------------------------------
__global__ __launch_bounds__(128) void reduce2_kernel(
    const float* __restrict__ P2, const float* __restrict__ hp2,
    float* __restrict__ out) {
  const int b = threadIdx.x;
  const int g = b >> 6;
  const int c = b & 63;
  float acc = 0.f;
  for (int s = 0; s < 8; ++s) acc += hp2[(size_t)s * BDIM + b];
  for (int s = 0; s < 8; ++s) acc += P2[(size_t)(g * 8 + s) * GCOLS + c];
  out[b] = acc;
}

extern "C" void kernel_launch(void* const* d_in, const int* in_sizes, int n_in,
                              void* d_out, int out_size, void* d_ws, size_t ws_size,
                              hipStream_t stream) {
  const float* x  = (const float*)d_in[0];
  const float* h  = (const float*)d_in[1];
  const float* J  = (const float*)d_in[2];
  const int*   ei = (const int*)d_in[3];
  const int*   ej = (const int*)d_in[4];
  float* out = (float*)d_out;

  const int N = in_sizes[1];   // 50000
  const int E = in_sizes[2];   // 1600000

  const int tblocks = (N + 63) / 64;

  // ws layout: xTh (2*N*64 halves) | P (2048*64) | P2 (16*64) | hp (tblocks*128) | hp2 (8*128)
  __half* xTh = (__half*)d_ws;
  float* P   = (float*)(xTh + (size_t)NGROUPS * N * GCOLS);
  float* P2  = P   + (size_t)NGROUPS * RANKS * GCOLS;
  float* hp  = P2  + (size_t)S1BLK * GCOLS;
  float* hp2 = hp  + (size_t)tblocks * BDIM;

  // 1) transpose + fp16 convert + h-term partials
  transpose_h_kernel<<<tblocks, 256, 0, stream>>>(x, h, xTh, hp, N);

  // 2) edge interactions (2 batch groups, XCD-quad affine, 128B-line gathers)
  const int epr = (E + RANKS - 1) / RANKS;
  edge_kernel<<<EBLK, 256, 0, stream>>>(xTh, J, ei, ej, P, E, N, epr);

  // 3) stage-1 reduce (edge partials + h partials)
  reduce1_kernel<<<S1BLK + HBLK2, 256, 0, stream>>>(P, hp, P2, hp2, tblocks);

  // 4) final deterministic reduce (overwrites d_out)
  reduce2_kernel<<<1, BDIM, 0, stream>>>(P2, hp2, out);
}